// Round 6
// baseline (459.647 us; speedup 1.0000x reference)
//
#include <hip/hip_runtime.h>
#include <hip/hip_bf16.h>
#include <math.h>

#define NHEADS 10

typedef unsigned short ushort_t;
typedef unsigned int uint_t;

__device__ __forceinline__ float bu2f(ushort_t u){ return __uint_as_float(((uint_t)u)<<16); }
__device__ __forceinline__ ushort_t f2bu(float f){
    uint_t b = __float_as_uint(f);
    return (ushort_t)((b + 0x7FFFu + ((b>>16)&1u)) >> 16);   // RNE
}

// ---------------- CSR build ----------------
__global__ void k_count(const int* eidx, int E, int N, int* cnt){
    int e = blockIdx.x*blockDim.x + threadIdx.x;
    int ET = E + N;
    if(e >= ET) return;
    int d = (e < E) ? eidx[E + e] : (e - E);
    atomicAdd(&cnt[d], 1);
}

__global__ void k_scan(int* cnt, int N, int ET, int* indptr){
    __shared__ int lds[1024];
    int t = threadIdx.x;
    int chunk = (N + 1023)/1024;
    int base = t*chunk;
    int s = 0;
    for(int i=0;i<chunk;i++){ int idx=base+i; if(idx<N) s += cnt[idx]; }
    lds[t]=s;
    __syncthreads();
    for(int off=1; off<1024; off<<=1){
        int v = (t>=off)? lds[t-off] : 0;
        __syncthreads();
        lds[t]+=v;
        __syncthreads();
    }
    int run = lds[t]-s;
    for(int i=0;i<chunk;i++){
        int idx=base+i;
        if(idx<N){
            int c = cnt[idx];
            indptr[idx]=run;
            cnt[idx]=run;
            run += c;
        }
    }
    if(t==0) indptr[N]=ET;
}

__global__ void k_fill(const int* eidx, int E, int N, int* cursor, int* srcs){
    int e = blockIdx.x*blockDim.x + threadIdx.x;
    int ET = E + N;
    if(e >= ET) return;
    int s, d;
    if(e < E){ s = eidx[e]; d = eidx[E+e]; } else { s = e-E; d = e-E; }
    int pos = atomicAdd(&cursor[d], 1);
    srcs[pos] = s;
}

// sort each node's src list ascending (canonical order + L2 temporal locality)
__global__ void k_sort(const int* indptr, int* srcs, int N){
    int n = blockIdx.x*blockDim.x + threadIdx.x;
    if(n>=N) return;
    int p0=indptr[n], p1=indptr[n+1];
    for(int i=p0+1;i<p1;i++){
        int v = srcs[i];
        int j = i-1;
        while(j>=p0 && srcs[j]>v){ srcs[j+1]=srcs[j]; j--; }
        srcs[j+1]=v;
    }
}

// ---------------- fc0: [N,24]@[24,16]+b, ELU ----------------
__global__ void k_fc0(const float* x, const float* W0, const float* b0, float* out, int N){
    int idx = blockIdx.x*blockDim.x+threadIdx.x;
    if(idx >= N*16) return;
    int n = idx>>4, c = idx&15;
    float acc = b0[c];
    #pragma unroll
    for(int k=0;k<24;k++) acc += x[n*24+k] * W0[k*16+c];
    out[idx] = acc>0.f ? acc : expm1f(acc);
}

// ---------------- tiled GEMM: C[N,HC] = A[N,K] @ B[K,HC] ----------------
// 64x64 tile / block, 256 threads, 4x4 micro-tile. unroll 8 (full unroll spilled: R3).
template<int K, int EPI, int OUTBF16>
__global__ void __launch_bounds__(256, 2)
k_gemm(const float* __restrict__ A, const float* __restrict__ B,
       const float* __restrict__ bias, void* __restrict__ Cmat,
       int N, int HC){
    constexpr int KC = (K > 64) ? 64 : K;
    __shared__ float As[64][K+1];
    __shared__ float Bs[KC][68];

    int t = threadIdx.x;
    int row0 = blockIdx.x*64;
    int col0 = blockIdx.y*64;

    for(int i=t; i<64*K; i+=256){
        int r = i/K, k = i%K;
        int row = row0 + r;
        As[r][k] = (row < N) ? A[(size_t)row*K + k] : 0.f;
    }

    int tr = t>>4, tc = t&15;
    int r0 = tr*4, c0 = tc*4;

    float acc[4][4];
    #pragma unroll
    for(int i=0;i<4;i++)
        #pragma unroll
        for(int j=0;j<4;j++) acc[i][j]=0.f;

    for(int kb=0; kb<K; kb+=KC){
        __syncthreads();
        for(int i=t; i<KC*64; i+=256){
            int k = i>>6, c = i&63;
            Bs[k][c] = B[(size_t)(kb+k)*HC + col0 + c];
        }
        __syncthreads();
        #pragma unroll 8
        for(int k=0;k<KC;k++){
            float4 b = *(const float4*)&Bs[k][c0];
            float a0 = As[r0+0][kb+k];
            float a1 = As[r0+1][kb+k];
            float a2 = As[r0+2][kb+k];
            float a3 = As[r0+3][kb+k];
            acc[0][0] += a0*b.x; acc[0][1] += a0*b.y; acc[0][2] += a0*b.z; acc[0][3] += a0*b.w;
            acc[1][0] += a1*b.x; acc[1][1] += a1*b.y; acc[1][2] += a1*b.z; acc[1][3] += a1*b.w;
            acc[2][0] += a2*b.x; acc[2][1] += a2*b.y; acc[2][2] += a2*b.z; acc[2][3] += a2*b.w;
            acc[3][0] += a3*b.x; acc[3][1] += a3*b.y; acc[3][2] += a3*b.z; acc[3][3] += a3*b.w;
        }
    }

    #pragma unroll
    for(int i=0;i<4;i++){
        int row = row0 + r0 + i;
        if(row >= N) continue;
        float4 v;
        v.x = acc[i][0]; v.y = acc[i][1]; v.z = acc[i][2]; v.w = acc[i][3];
        if(EPI){
            v.x += bias[col0+c0+0]; v.y += bias[col0+c0+1];
            v.z += bias[col0+c0+2]; v.w += bias[col0+c0+3];
            v.x = v.x>0.f? v.x : expm1f(v.x);
            v.y = v.y>0.f? v.y : expm1f(v.y);
            v.z = v.z>0.f? v.z : expm1f(v.z);
            v.w = v.w>0.f? v.w : expm1f(v.w);
        }
        if(OUTBF16){
            ushort4 u;
            u.x = f2bu(v.x); u.y = f2bu(v.y); u.z = f2bu(v.z); u.w = f2bu(v.w);
            *(ushort4*)&((ushort_t*)Cmat)[(size_t)row*HC + col0 + c0] = u;
        } else {
            *(float4*)&((float*)Cmat)[(size_t)row*HC + col0 + c0] = v;
        }
    }
}

// ---------------- attention logits per (n,h), bf16 hf ----------------
template<int C>
__global__ void k_attn(const ushort_t* hf, const float* a_s, const float* a_d,
                       float* es, float* ed, int N){
    int idx = blockIdx.x*blockDim.x+threadIdx.x;
    if(idx >= N*NHEADS) return;
    int n = idx/NHEADS, h = idx%NHEADS;
    const uint4* hp = reinterpret_cast<const uint4*>(hf + (size_t)n*NHEADS*C + h*C);
    float s=0.f, d=0.f;
    #pragma unroll
    for(int cb=0; cb<C/8; cb++){
        uint4 q = hp[cb];
        uint_t uu[4] = {q.x, q.y, q.z, q.w};
        #pragma unroll
        for(int j=0;j<4;j++){
            float f0 = __uint_as_float(uu[j]<<16);
            float f1 = __uint_as_float(uu[j] & 0xFFFF0000u);
            int c = cb*8 + j*2;
            s += f0*a_s[h*C+c]   + f1*a_s[h*C+c+1];
            d += f0*a_d[h*C+c]   + f1*a_d[h*C+c+1];
        }
    }
    es[idx]=s; ed[idx]=d;
}

// ---------------- softmax stats: pass1 online max+den (caches leaky logit), pass2 normalize ----------------
__global__ void k_stats(const int* indptr, const int* srcs, const float* es, const float* ed,
                        float* wbuf, int N){
    int idx = blockIdx.x*blockDim.x+threadIdx.x;
    if(idx >= N*NHEADS) return;
    int n = idx/NHEADS, h = idx%NHEADS;
    int p0 = indptr[n], p1 = indptr[n+1];
    float edv = ed[idx];
    float m = -1e30f, den = 0.f;
    for(int p=p0;p<p1;p++){
        float v = es[srcs[p]*NHEADS+h] + edv;
        v = (v>=0.f)? v : 0.2f*v;
        wbuf[(size_t)p*NHEADS+h] = v;
        float nm = fmaxf(m, v);
        den = den*expf(m-nm) + expf(v-nm);
        m = nm;
    }
    float dinv = 1.f/(den+1e-16f);
    for(int p=p0;p<p1;p++){
        float v = wbuf[(size_t)p*NHEADS+h];
        wbuf[(size_t)p*NHEADS+h] = expf(v-m)*dinv;
    }
}

// ---------------- aggregation: bf16 hf gather, 2 channels/thread ----------------
template<int C>
__global__ void k_agg(const int* indptr, const int* srcs, const float* wbuf,
                      const ushort_t* hf, const float* bc, float* out, int N){
    constexpr int TPN = C/2;          // threads per node
    constexpr int NPB = 256/TPN;      // nodes per block
    int local = threadIdx.x % TPN;
    int n = blockIdx.x*NPB + threadIdx.x/TPN;
    if(n>=N) return;
    int c2 = local*2;
    int p0=indptr[n], p1=indptr[n+1];
    float acc0=0.f, acc1=0.f;
    for(int p=p0;p<p1;p++){
        int s = srcs[p];
        const ushort_t* hp = hf + (size_t)s*NHEADS*C + c2;
        const float* wp = wbuf + (size_t)p*NHEADS;
        #pragma unroll
        for(int h=0;h<NHEADS;h++){
            uint_t u = *(const uint_t*)(hp + h*C);
            float w = wp[h];
            acc0 += w * __uint_as_float(u<<16);
            acc1 += w * __uint_as_float(u & 0xFFFF0000u);
        }
    }
    float v0 = acc0*(1.f/NHEADS) + bc[c2];
    float v1 = acc1*(1.f/NHEADS) + bc[c2+1];
    out[(size_t)n*C + c2]     = v0>0.f? v0 : expm1f(v0);
    out[(size_t)n*C + c2 + 1] = v1>0.f? v1 : expm1f(v1);
}

// ---------------- head: logits 256->24 + log_softmax ----------------
__global__ void k_head(const float* hin, const float* W2, const float* b2v, float* out, int N){
    int grp  = threadIdx.x/32;
    int lane = threadIdx.x%32;
    int n = blockIdx.x*8 + grp;
    if(n>=N) return;
    float acc = -1e30f;
    if(lane < 24){
        acc = b2v[lane];
        for(int k=0;k<256;k++) acc += hin[n*256+k]*W2[k*24+lane];
    }
    float mx = acc;
    for(int off=16; off; off>>=1) mx = fmaxf(mx, __shfl_xor(mx, off, 32));
    float ex = (lane<24)? expf(acc-mx) : 0.f;
    float sm = ex;
    for(int off=16; off; off>>=1) sm += __shfl_xor(sm, off, 32);
    if(lane<24) out[n*24+lane] = acc - mx - logf(sm);
}

extern "C" void kernel_launch(void* const* d_in, const int* in_sizes, int n_in,
                              void* d_out, int out_size, void* d_ws, size_t ws_size,
                              hipStream_t stream) {
    const float* x   = (const float*)d_in[0];
    const int*  eidx = (const int*)d_in[1];
    const float* W0 = (const float*)d_in[3];  const float* b0 = (const float*)d_in[4];
    const float* Wc1= (const float*)d_in[5];  const float* as1= (const float*)d_in[6];
    const float* ad1= (const float*)d_in[7];  const float* bc1= (const float*)d_in[8];
    const float* Wc2= (const float*)d_in[9];  const float* as2= (const float*)d_in[10];
    const float* ad2= (const float*)d_in[11]; const float* bc2= (const float*)d_in[12];
    const float* Wc3= (const float*)d_in[13]; const float* as3= (const float*)d_in[14];
    const float* ad3= (const float*)d_in[15]; const float* bc3= (const float*)d_in[16];
    const float* W1 = (const float*)d_in[17]; const float* b1 = (const float*)d_in[18];
    const float* W2 = (const float*)d_in[19]; const float* b2 = (const float*)d_in[20];
    float* out = (float*)d_out;

    const int N  = in_sizes[0]/24;
    const int E  = in_sizes[1]/2;
    const int ET = E + N;

    char* w = (char*)d_ws;
    size_t off = 0;
    auto alloc = [&](size_t bytes)->void* {
        void* p = w + off;
        off = (off + bytes + 255) & ~(size_t)255;
        return p;
    };
    int*   cnt    = (int*)  alloc((size_t)N*4);
    int*   indptr = (int*)  alloc((size_t)(N+1)*4);
    int*   srcs   = (int*)  alloc((size_t)ET*4);
    float* es     = (float*)alloc((size_t)N*NHEADS*4);
    float* ed     = (float*)alloc((size_t)N*NHEADS*4);
    float* wbuf   = (float*)alloc((size_t)ET*NHEADS*4);
    float* nfA    = (float*)alloc((size_t)N*256*4);
    float* nfB    = (float*)alloc((size_t)N*256*4);
    ushort_t* hf  = (ushort_t*)alloc((size_t)N*1280*2);

    // CSR by dst
    hipMemsetAsync(cnt, 0, (size_t)N*4, stream);
    int gE = (ET+255)/256;
    k_count<<<gE,256,0,stream>>>(eidx, E, N, cnt);
    k_scan <<<1,1024,0,stream>>>(cnt, N, ET, indptr);
    k_fill <<<gE,256,0,stream>>>(eidx, E, N, cnt, srcs);
    k_sort <<<(N+255)/256,256,0,stream>>>(indptr, srcs, N);

    int gNH = (N*NHEADS+255)/256;
    int gRow = (N+63)/64;

    // fc0
    k_fc0<<<(N*16+255)/256,256,0,stream>>>(x, W0, b0, nfA, N);

    // GAT1: 16 -> H x 32
    k_gemm<16,0,1><<<dim3(gRow,320/64),256,0,stream>>>(nfA, Wc1, nullptr, hf, N, 320);
    k_attn<32><<<gNH,256,0,stream>>>(hf, as1, ad1, es, ed, N);
    k_stats<<<gNH,256,0,stream>>>(indptr, srcs, es, ed, wbuf, N);
    k_agg<32><<<(N*16+255)/256,256,0,stream>>>(indptr, srcs, wbuf, hf, bc1, nfB, N);

    // GAT2: 32 -> H x 64
    k_gemm<32,0,1><<<dim3(gRow,640/64),256,0,stream>>>(nfB, Wc2, nullptr, hf, N, 640);
    k_attn<64><<<gNH,256,0,stream>>>(hf, as2, ad2, es, ed, N);
    k_stats<<<gNH,256,0,stream>>>(indptr, srcs, es, ed, wbuf, N);
    k_agg<64><<<(N*32+255)/256,256,0,stream>>>(indptr, srcs, wbuf, hf, bc2, nfA, N);

    // GAT3: 64 -> H x 128
    k_gemm<64,0,1><<<dim3(gRow,1280/64),256,0,stream>>>(nfA, Wc3, nullptr, hf, N, 1280);
    k_attn<128><<<gNH,256,0,stream>>>(hf, as3, ad3, es, ed, N);
    k_stats<<<gNH,256,0,stream>>>(indptr, srcs, es, ed, wbuf, N);
    k_agg<128><<<(N*64+255)/256,256,0,stream>>>(indptr, srcs, wbuf, hf, bc3, nfB, N);

    // fc1: [N,128]@[128,256] + bias + ELU (f32 out)
    k_gemm<128,1,0><<<dim3(gRow,256/64),256,0,stream>>>(nfB, W1, b1, nfA, N, 256);
    // head
    k_head<<<(N+7)/8,256,0,stream>>>(nfA, W2, b2, out, N);
}

// Round 7
// 380.503 us; speedup vs baseline: 1.2080x; 1.2080x over previous
//
#include <hip/hip_runtime.h>
#include <hip/hip_bf16.h>
#include <math.h>

#define NHEADS 10

typedef unsigned short ushort_t;
typedef unsigned int uint_t;

__device__ __forceinline__ float bu2f(ushort_t u){ return __uint_as_float(((uint_t)u)<<16); }
__device__ __forceinline__ ushort_t f2bu(float f){
    uint_t b = __float_as_uint(f);
    return (ushort_t)((b + 0x7FFFu + ((b>>16)&1u)) >> 16);   // RNE
}

// ---------------- CSR build ----------------
__global__ void k_count(const int* eidx, int E, int N, int* cnt){
    int e = blockIdx.x*blockDim.x + threadIdx.x;
    int ET = E + N;
    if(e >= ET) return;
    int d = (e < E) ? eidx[E + e] : (e - E);
    atomicAdd(&cnt[d], 1);
}

__global__ void k_scan(int* cnt, int N, int ET, int* indptr){
    __shared__ int lds[1024];
    int t = threadIdx.x;
    int chunk = (N + 1023)/1024;
    int base = t*chunk;
    int s = 0;
    for(int i=0;i<chunk;i++){ int idx=base+i; if(idx<N) s += cnt[idx]; }
    lds[t]=s;
    __syncthreads();
    for(int off=1; off<1024; off<<=1){
        int v = (t>=off)? lds[t-off] : 0;
        __syncthreads();
        lds[t]+=v;
        __syncthreads();
    }
    int run = lds[t]-s;
    for(int i=0;i<chunk;i++){
        int idx=base+i;
        if(idx<N){
            int c = cnt[idx];
            indptr[idx]=run;
            cnt[idx]=run;
            run += c;
        }
    }
    if(t==0) indptr[N]=ET;
}

__global__ void k_fill(const int* eidx, int E, int N, int* cursor, int* srcs){
    int e = blockIdx.x*blockDim.x + threadIdx.x;
    int ET = E + N;
    if(e >= ET) return;
    int s, d;
    if(e < E){ s = eidx[e]; d = eidx[E+e]; } else { s = e-E; d = e-E; }
    int pos = atomicAdd(&cursor[d], 1);
    srcs[pos] = s;
}

// wave-parallel bitonic sort of each node's src segment (1 wave / node)
__global__ void k_sortw(const int* indptr, int* srcs, int N){
    int wid  = (blockIdx.x*blockDim.x + threadIdx.x) >> 6;
    int lane = threadIdx.x & 63;
    if(wid >= N) return;
    int p0 = indptr[wid], p1 = indptr[wid+1];
    int deg = p1 - p0;
    if(deg <= 1) return;
    if(deg <= 64){
        int v = (lane < deg) ? srcs[p0+lane] : 0x7FFFFFFF;
        #pragma unroll
        for(int k=2; k<=64; k<<=1){
            #pragma unroll
            for(int j=k>>1; j>0; j>>=1){
                int partner = __shfl_xor(v, j, 64);
                bool dir   = ((lane & k) == 0);
                bool small = ((lane & j) == 0);
                int mn = min(v, partner), mx = max(v, partner);
                v = (dir == small) ? mn : mx;
            }
        }
        if(lane < deg) srcs[p0+lane] = v;
    } else if(lane == 0){               // safety fallback, statistically never
        for(int i=p0+1;i<p1;i++){
            int v2 = srcs[i]; int j=i-1;
            while(j>=p0 && srcs[j]>v2){ srcs[j+1]=srcs[j]; j--; }
            srcs[j+1]=v2;
        }
    }
}

// ---------------- fc0: [N,24]@[24,16]+b, ELU ----------------
__global__ void k_fc0(const float* x, const float* W0, const float* b0, float* out, int N){
    int idx = blockIdx.x*blockDim.x+threadIdx.x;
    if(idx >= N*16) return;
    int n = idx>>4, c = idx&15;
    float acc = b0[c];
    #pragma unroll
    for(int k=0;k<24;k++) acc += x[n*24+k] * W0[k*16+c];
    out[idx] = acc>0.f ? acc : expm1f(acc);
}

// ---------------- tiled GEMM: C[N,HC] = A[N,K] @ B[K,HC] ----------------
// 64x64 tile / block, 256 threads, 4x4 micro-tile. unroll 8 (full unroll spilled: R3).
template<int K, int EPI, int OUTBF16>
__global__ void __launch_bounds__(256, 2)
k_gemm(const float* __restrict__ A, const float* __restrict__ B,
       const float* __restrict__ bias, void* __restrict__ Cmat,
       int N, int HC){
    constexpr int KC = (K > 64) ? 64 : K;
    __shared__ float As[64][K+1];
    __shared__ float Bs[KC][68];

    int t = threadIdx.x;
    int row0 = blockIdx.x*64;
    int col0 = blockIdx.y*64;

    for(int i=t; i<64*K; i+=256){
        int r = i/K, k = i%K;
        int row = row0 + r;
        As[r][k] = (row < N) ? A[(size_t)row*K + k] : 0.f;
    }

    int tr = t>>4, tc = t&15;
    int r0 = tr*4, c0 = tc*4;

    float acc[4][4];
    #pragma unroll
    for(int i=0;i<4;i++)
        #pragma unroll
        for(int j=0;j<4;j++) acc[i][j]=0.f;

    for(int kb=0; kb<K; kb+=KC){
        __syncthreads();
        for(int i=t; i<KC*64; i+=256){
            int k = i>>6, c = i&63;
            Bs[k][c] = B[(size_t)(kb+k)*HC + col0 + c];
        }
        __syncthreads();
        #pragma unroll 8
        for(int k=0;k<KC;k++){
            float4 b = *(const float4*)&Bs[k][c0];
            float a0 = As[r0+0][kb+k];
            float a1 = As[r0+1][kb+k];
            float a2 = As[r0+2][kb+k];
            float a3 = As[r0+3][kb+k];
            acc[0][0] += a0*b.x; acc[0][1] += a0*b.y; acc[0][2] += a0*b.z; acc[0][3] += a0*b.w;
            acc[1][0] += a1*b.x; acc[1][1] += a1*b.y; acc[1][2] += a1*b.z; acc[1][3] += a1*b.w;
            acc[2][0] += a2*b.x; acc[2][1] += a2*b.y; acc[2][2] += a2*b.z; acc[2][3] += a2*b.w;
            acc[3][0] += a3*b.x; acc[3][1] += a3*b.y; acc[3][2] += a3*b.z; acc[3][3] += a3*b.w;
        }
    }

    #pragma unroll
    for(int i=0;i<4;i++){
        int row = row0 + r0 + i;
        if(row >= N) continue;
        float4 v;
        v.x = acc[i][0]; v.y = acc[i][1]; v.z = acc[i][2]; v.w = acc[i][3];
        if(EPI){
            v.x += bias[col0+c0+0]; v.y += bias[col0+c0+1];
            v.z += bias[col0+c0+2]; v.w += bias[col0+c0+3];
            v.x = v.x>0.f? v.x : expm1f(v.x);
            v.y = v.y>0.f? v.y : expm1f(v.y);
            v.z = v.z>0.f? v.z : expm1f(v.z);
            v.w = v.w>0.f? v.w : expm1f(v.w);
        }
        if(OUTBF16){
            ushort4 u;
            u.x = f2bu(v.x); u.y = f2bu(v.y); u.z = f2bu(v.z); u.w = f2bu(v.w);
            *(ushort4*)&((ushort_t*)Cmat)[(size_t)row*HC + col0 + c0] = u;
        } else {
            *(float4*)&((float*)Cmat)[(size_t)row*HC + col0 + c0] = v;
        }
    }
}

// ---------------- attention logits per (n,h), bf16 hf ----------------
template<int C>
__global__ void k_attn(const ushort_t* hf, const float* a_s, const float* a_d,
                       float* es, float* ed, int N){
    int idx = blockIdx.x*blockDim.x+threadIdx.x;
    if(idx >= N*NHEADS) return;
    int n = idx/NHEADS, h = idx%NHEADS;
    const uint4* hp = reinterpret_cast<const uint4*>(hf + (size_t)n*NHEADS*C + h*C);
    float s=0.f, d=0.f;
    #pragma unroll
    for(int cb=0; cb<C/8; cb++){
        uint4 q = hp[cb];
        uint_t uu[4] = {q.x, q.y, q.z, q.w};
        #pragma unroll
        for(int j=0;j<4;j++){
            float f0 = __uint_as_float(uu[j]<<16);
            float f1 = __uint_as_float(uu[j] & 0xFFFF0000u);
            int c = cb*8 + j*2;
            s += f0*a_s[h*C+c]   + f1*a_s[h*C+c+1];
            d += f0*a_d[h*C+c]   + f1*a_d[h*C+c+1];
        }
    }
    es[idx]=s; ed[idx]=d;
}

// ---------------- softmax stats: pass1 online max+den (caches leaky logit), pass2 normalize ----------------
__global__ void k_stats(const int* indptr, const int* srcs, const float* es, const float* ed,
                        float* wbuf, int N){
    int idx = blockIdx.x*blockDim.x+threadIdx.x;
    if(idx >= N*NHEADS) return;
    int n = idx/NHEADS, h = idx%NHEADS;
    int p0 = indptr[n], p1 = indptr[n+1];
    float edv = ed[idx];
    float m = -1e30f, den = 0.f;
    for(int p=p0;p<p1;p++){
        float v = es[srcs[p]*NHEADS+h] + edv;
        v = (v>=0.f)? v : 0.2f*v;
        wbuf[(size_t)p*NHEADS+h] = v;
        float nm = fmaxf(m, v);
        den = den*expf(m-nm) + expf(v-nm);
        m = nm;
    }
    float dinv = 1.f/(den+1e-16f);
    for(int p=p0;p<p1;p++){
        float v = wbuf[(size_t)p*NHEADS+h];
        wbuf[(size_t)p*NHEADS+h] = expf(v-m)*dinv;
    }
}

// ---------------- aggregation: bf16 hf gather, 2 channels/thread ----------------
template<int C>
__global__ void k_agg(const int* indptr, const int* srcs, const float* wbuf,
                      const ushort_t* hf, const float* bc, float* out, int N){
    constexpr int TPN = C/2;          // threads per node
    constexpr int NPB = 256/TPN;      // nodes per block
    int local = threadIdx.x % TPN;
    int n = blockIdx.x*NPB + threadIdx.x/TPN;
    if(n>=N) return;
    int c2 = local*2;
    int p0=indptr[n], p1=indptr[n+1];
    float acc0=0.f, acc1=0.f;
    for(int p=p0;p<p1;p++){
        int s = srcs[p];
        const ushort_t* hp = hf + (size_t)s*NHEADS*C + c2;
        const float* wp = wbuf + (size_t)p*NHEADS;
        #pragma unroll
        for(int h=0;h<NHEADS;h++){
            uint_t u = *(const uint_t*)(hp + h*C);
            float w = wp[h];
            acc0 += w * __uint_as_float(u<<16);
            acc1 += w * __uint_as_float(u & 0xFFFF0000u);
        }
    }
    float v0 = acc0*(1.f/NHEADS) + bc[c2];
    float v1 = acc1*(1.f/NHEADS) + bc[c2+1];
    out[(size_t)n*C + c2]     = v0>0.f? v0 : expm1f(v0);
    out[(size_t)n*C + c2 + 1] = v1>0.f? v1 : expm1f(v1);
}

// ---------------- head: logits 256->24 + log_softmax ----------------
__global__ void k_head(const float* hin, const float* W2, const float* b2v, float* out, int N){
    int grp  = threadIdx.x/32;
    int lane = threadIdx.x%32;
    int n = blockIdx.x*8 + grp;
    if(n>=N) return;
    float acc = -1e30f;
    if(lane < 24){
        acc = b2v[lane];
        for(int k=0;k<256;k++) acc += hin[n*256+k]*W2[k*24+lane];
    }
    float mx = acc;
    for(int off=16; off; off>>=1) mx = fmaxf(mx, __shfl_xor(mx, off, 32));
    float ex = (lane<24)? expf(acc-mx) : 0.f;
    float sm = ex;
    for(int off=16; off; off>>=1) sm += __shfl_xor(sm, off, 32);
    if(lane<24) out[n*24+lane] = acc - mx - logf(sm);
}

extern "C" void kernel_launch(void* const* d_in, const int* in_sizes, int n_in,
                              void* d_out, int out_size, void* d_ws, size_t ws_size,
                              hipStream_t stream) {
    const float* x   = (const float*)d_in[0];
    const int*  eidx = (const int*)d_in[1];
    const float* W0 = (const float*)d_in[3];  const float* b0 = (const float*)d_in[4];
    const float* Wc1= (const float*)d_in[5];  const float* as1= (const float*)d_in[6];
    const float* ad1= (const float*)d_in[7];  const float* bc1= (const float*)d_in[8];
    const float* Wc2= (const float*)d_in[9];  const float* as2= (const float*)d_in[10];
    const float* ad2= (const float*)d_in[11]; const float* bc2= (const float*)d_in[12];
    const float* Wc3= (const float*)d_in[13]; const float* as3= (const float*)d_in[14];
    const float* ad3= (const float*)d_in[15]; const float* bc3= (const float*)d_in[16];
    const float* W1 = (const float*)d_in[17]; const float* b1 = (const float*)d_in[18];
    const float* W2 = (const float*)d_in[19]; const float* b2 = (const float*)d_in[20];
    float* out = (float*)d_out;

    const int N  = in_sizes[0]/24;
    const int E  = in_sizes[1]/2;
    const int ET = E + N;

    char* w = (char*)d_ws;
    size_t off = 0;
    auto alloc = [&](size_t bytes)->void* {
        void* p = w + off;
        off = (off + bytes + 255) & ~(size_t)255;
        return p;
    };
    int*   cnt    = (int*)  alloc((size_t)N*4);
    int*   indptr = (int*)  alloc((size_t)(N+1)*4);
    int*   srcs   = (int*)  alloc((size_t)ET*4);
    float* es     = (float*)alloc((size_t)N*NHEADS*4);
    float* ed     = (float*)alloc((size_t)N*NHEADS*4);
    float* wbuf   = (float*)alloc((size_t)ET*NHEADS*4);
    float* nfA    = (float*)alloc((size_t)N*256*4);
    float* nfB    = (float*)alloc((size_t)N*256*4);
    ushort_t* hf  = (ushort_t*)alloc((size_t)N*1280*2);

    // CSR by dst
    hipMemsetAsync(cnt, 0, (size_t)N*4, stream);
    int gE = (ET+255)/256;
    k_count<<<gE,256,0,stream>>>(eidx, E, N, cnt);
    k_scan <<<1,1024,0,stream>>>(cnt, N, ET, indptr);
    k_fill <<<gE,256,0,stream>>>(eidx, E, N, cnt, srcs);
    k_sortw<<<((size_t)N*64+255)/256,256,0,stream>>>(indptr, srcs, N);

    int gNH = (N*NHEADS+255)/256;
    int gRow = (N+63)/64;

    // fc0
    k_fc0<<<(N*16+255)/256,256,0,stream>>>(x, W0, b0, nfA, N);

    // GAT1: 16 -> H x 32
    k_gemm<16,0,1><<<dim3(gRow,320/64),256,0,stream>>>(nfA, Wc1, nullptr, hf, N, 320);
    k_attn<32><<<gNH,256,0,stream>>>(hf, as1, ad1, es, ed, N);
    k_stats<<<gNH,256,0,stream>>>(indptr, srcs, es, ed, wbuf, N);
    k_agg<32><<<(N*16+255)/256,256,0,stream>>>(indptr, srcs, wbuf, hf, bc1, nfB, N);

    // GAT2: 32 -> H x 64
    k_gemm<32,0,1><<<dim3(gRow,640/64),256,0,stream>>>(nfB, Wc2, nullptr, hf, N, 640);
    k_attn<64><<<gNH,256,0,stream>>>(hf, as2, ad2, es, ed, N);
    k_stats<<<gNH,256,0,stream>>>(indptr, srcs, es, ed, wbuf, N);
    k_agg<64><<<(N*32+255)/256,256,0,stream>>>(indptr, srcs, wbuf, hf, bc2, nfA, N);

    // GAT3: 64 -> H x 128
    k_gemm<64,0,1><<<dim3(gRow,1280/64),256,0,stream>>>(nfA, Wc3, nullptr, hf, N, 1280);
    k_attn<128><<<gNH,256,0,stream>>>(hf, as3, ad3, es, ed, N);
    k_stats<<<gNH,256,0,stream>>>(indptr, srcs, es, ed, wbuf, N);
    k_agg<128><<<(N*64+255)/256,256,0,stream>>>(indptr, srcs, wbuf, hf, bc3, nfB, N);

    // fc1: [N,128]@[128,256] + bias + ELU (f32 out)
    k_gemm<128,1,0><<<dim3(gRow,256/64),256,0,stream>>>(nfB, W1, b1, nfA, N, 256);
    // head
    k_head<<<(N+7)/8,256,0,stream>>>(nfA, W2, b2, out, N);
}